// Round 1
// baseline (465.844 us; speedup 1.0000x reference)
//
#include <hip/hip_runtime.h>
#include <hip/hip_bf16.h>

// Problem constants (B,R,M,L,H) = (256, 2048, 65536, 64, 4)
#define BB   256
#define RR   2048
#define MM   65536
#define LL   64
#define HH   4
#define NROW (BB*HH)   // 1024 (b,h) rows
#define KEYS (HH*LL)   // 256 key outputs per batch
#define MROWS 16       // rows per block in main kernels
#define MTILE 1024     // m-slots per block (256 thr * float4)

typedef float f4v __attribute__((ext_vector_type(4)));

// ---------------- generic 64x64 tiled transpose: out[c][r] = in[r][c] ----------------
__global__ __launch_bounds__(256) void transpose_k(const float* __restrict__ in,
                                                   float* __restrict__ out,
                                                   int NR, int NC) {
    __shared__ float t[64 * 65];
    int r0 = blockIdx.x * 64, c0 = blockIdx.y * 64;
    int lane = threadIdx.x & 63, w = threadIdx.x >> 6;
#pragma unroll
    for (int i = 0; i < 16; ++i) {
        int rr = i * 4 + w;
        t[lane * 65 + rr] = in[(size_t)(r0 + rr) * NC + c0 + lane];
    }
    __syncthreads();
#pragma unroll
    for (int i = 0; i < 16; ++i) {
        int cc = i * 4 + w;
        out[(size_t)(c0 + cc) * NR + r0 + lane] = t[cc * 65 + lane];
    }
}

// ---------------- K0: split-k partial keys GEMM: kpart[kc][b][j] = sum_k S[b][k]*WkT[k][j] ----
__global__ __launch_bounds__(256) void k0_keys(const float* __restrict__ S,
                                               const float* __restrict__ WkT,
                                               float* __restrict__ kpart) {
    __shared__ float sl[8 * 256];
    int bg  = blockIdx.x;   // 0..31, 8 batches each
    int kc  = blockIdx.y;   // 0..7, 256 k each
    int tid = threadIdx.x;
    int b0  = bg * 8;
#pragma unroll
    for (int bi = 0; bi < 8; ++bi)
        sl[bi * 256 + tid] = S[(size_t)(b0 + bi) * RR + kc * 256 + tid];
    __syncthreads();
    float acc[8] = {0, 0, 0, 0, 0, 0, 0, 0};
    const float* wp = WkT + (size_t)kc * 256 * KEYS + tid;
#pragma unroll 4
    for (int kk = 0; kk < 256; ++kk) {
        float wv = wp[kk * KEYS];
#pragma unroll
        for (int bi = 0; bi < 8; ++bi)
            acc[bi] = fmaf(sl[bi * 256 + kk], wv, acc[bi]);
    }
    float* op = kpart + (size_t)kc * BB * KEYS + (size_t)b0 * KEYS + tid;
#pragma unroll
    for (int bi = 0; bi < 8; ++bi)
        op[bi * KEYS] = acc[bi];
}

// ---------------- K1: per-(b,h): beta, key-norm, write qT[l][bh] = keys*beta/norm ----------
__global__ __launch_bounds__(256) void k1_finalize(const float* __restrict__ S,
                                                   const float* __restrict__ kpart,
                                                   const float* __restrict__ bk,
                                                   const float* __restrict__ Wb,
                                                   const float* __restrict__ bb,
                                                   float* __restrict__ qT) {
    int bh = blockIdx.x, b = bh >> 2, h = bh & 3;
    int tid = threadIdx.x, lane = tid & 63, w = tid >> 6;
    // beta = relu(S[b]·Wb[h] + bb[h]) via block reduction
    float p = 0.f;
#pragma unroll
    for (int i = 0; i < 8; ++i) {
        int k = i * 256 + tid;
        p += S[(size_t)b * RR + k] * Wb[(size_t)h * RR + k];
    }
#pragma unroll
    for (int off = 32; off > 0; off >>= 1) p += __shfl_down(p, off, 64);
    __shared__ float red[4];
    if (lane == 0) red[w] = p;
    __syncthreads();
    if (tid < 64) {
        float beta = red[0] + red[1] + red[2] + red[3] + bb[h];
        beta = beta > 0.f ? beta : 0.f;
        int l = lane;
        float kv = bk[h * LL + l];
#pragma unroll
        for (int c = 0; c < 8; ++c)
            kv += kpart[(size_t)c * BB * KEYS + (size_t)b * KEYS + h * LL + l];
        float sq = kv * kv;
#pragma unroll
        for (int off = 1; off < 64; off <<= 1) sq += __shfl_xor(sq, off, 64);
        float scale = beta / sqrtf(sq);
        qT[(size_t)l * NROW + bh] = kv * scale;
    }
}

// ---------------- K2: per (row-group, m-tile): per-wave partial max & sumexp -----------
__global__ __launch_bounds__(256) void k2_partial(const float* __restrict__ memT,
                                                  const float* __restrict__ qT,
                                                  float* __restrict__ pmax,
                                                  float* __restrict__ psum) {
    int bx = blockIdx.x;
    int mtile = bx >> 6, rg = bx & 63;
    int r0 = rg * MROWS;
    int tid = threadIdx.x, lane = tid & 63, w = tid >> 6;
    int m = mtile * MTILE + tid * 4;
    const float* qp = (const float*)__builtin_assume_aligned(qT + r0, 64);
    const float* mp = memT + m;
    float acc[MROWS][4];
#pragma unroll
    for (int r = 0; r < MROWS; ++r)
        acc[r][0] = acc[r][1] = acc[r][2] = acc[r][3] = 0.f;
#pragma unroll 4
    for (int l = 0; l < LL; ++l) {
        float4 v = *(const float4*)(mp + (size_t)l * MM);
#pragma unroll
        for (int r = 0; r < MROWS; ++r) {
            float qv = qp[l * NROW + r];   // wave-uniform -> s_load
            acc[r][0] = fmaf(qv, v.x, acc[r][0]);
            acc[r][1] = fmaf(qv, v.y, acc[r][1]);
            acc[r][2] = fmaf(qv, v.z, acc[r][2]);
            acc[r][3] = fmaf(qv, v.w, acc[r][3]);
        }
    }
    int col = mtile * 4 + w;  // 256 per-wave partials per row
#pragma unroll
    for (int r = 0; r < MROWS; ++r) {
        float mx = fmaxf(fmaxf(acc[r][0], acc[r][1]), fmaxf(acc[r][2], acc[r][3]));
#pragma unroll
        for (int off = 1; off < 64; off <<= 1) mx = fmaxf(mx, __shfl_xor(mx, off, 64));
        float s = __expf(acc[r][0] - mx) + __expf(acc[r][1] - mx)
                + __expf(acc[r][2] - mx) + __expf(acc[r][3] - mx);
#pragma unroll
        for (int off = 1; off < 64; off <<= 1) s += __shfl_xor(s, off, 64);
        if (lane == 0) {
            pmax[(size_t)(r0 + r) * 256 + col] = mx;
            psum[(size_t)(r0 + r) * 256 + col] = s;
        }
    }
}

// ---------------- K3: combine 256 per-wave partials per row -> (gmax, 1/gsum) ---------
__global__ __launch_bounds__(256) void k3_combine(const float* __restrict__ pmax,
                                                  const float* __restrict__ psum,
                                                  float* __restrict__ rstat) {
    int row = blockIdx.x, tid = threadIdx.x, lane = tid & 63, w = tid >> 6;
    float my_max = pmax[(size_t)row * 256 + tid];
    float my_sum = psum[(size_t)row * 256 + tid];
    float mx = my_max;
#pragma unroll
    for (int off = 1; off < 64; off <<= 1) mx = fmaxf(mx, __shfl_xor(mx, off, 64));
    __shared__ float wm[4], wsum[4];
    if (lane == 0) wm[w] = mx;
    __syncthreads();
    float gmax = fmaxf(fmaxf(wm[0], wm[1]), fmaxf(wm[2], wm[3]));
    float c = my_sum * __expf(my_max - gmax);
#pragma unroll
    for (int off = 1; off < 64; off <<= 1) c += __shfl_xor(c, off, 64);
    if (lane == 0) wsum[w] = c;
    __syncthreads();
    if (tid == 0) {
        float gs = wsum[0] + wsum[1] + wsum[2] + wsum[3];
        rstat[row * 2]     = gmax;
        rstat[row * 2 + 1] = 1.0f / gs;
    }
}

// ---------------- K4: recompute dots, write normalized softmax ------------------------
__global__ __launch_bounds__(256) void k4_out(const float* __restrict__ memT,
                                              const float* __restrict__ qT,
                                              const float* __restrict__ rstat,
                                              float* __restrict__ out) {
    int bx = blockIdx.x;
    int mtile = bx >> 6, rg = bx & 63;
    int r0 = rg * MROWS;
    int tid = threadIdx.x;
    int m = mtile * MTILE + tid * 4;
    const float* qp = (const float*)__builtin_assume_aligned(qT + r0, 64);
    const float* mp = memT + m;
    float acc[MROWS][4];
#pragma unroll
    for (int r = 0; r < MROWS; ++r)
        acc[r][0] = acc[r][1] = acc[r][2] = acc[r][3] = 0.f;
#pragma unroll 4
    for (int l = 0; l < LL; ++l) {
        float4 v = *(const float4*)(mp + (size_t)l * MM);
#pragma unroll
        for (int r = 0; r < MROWS; ++r) {
            float qv = qp[l * NROW + r];   // wave-uniform -> s_load
            acc[r][0] = fmaf(qv, v.x, acc[r][0]);
            acc[r][1] = fmaf(qv, v.y, acc[r][1]);
            acc[r][2] = fmaf(qv, v.z, acc[r][2]);
            acc[r][3] = fmaf(qv, v.w, acc[r][3]);
        }
    }
#pragma unroll
    for (int r = 0; r < MROWS; ++r) {
        float gmax = rstat[(r0 + r) * 2];       // wave-uniform
        float gin  = rstat[(r0 + r) * 2 + 1];
        f4v o;
        o.x = __expf(acc[r][0] - gmax) * gin;
        o.y = __expf(acc[r][1] - gmax) * gin;
        o.z = __expf(acc[r][2] - gmax) * gin;
        o.w = __expf(acc[r][3] - gmax) * gin;
        __builtin_nontemporal_store(o, (f4v*)(out + (size_t)(r0 + r) * MM + m));
    }
}

extern "C" void kernel_launch(void* const* d_in, const int* in_sizes, int n_in,
                              void* d_out, int out_size, void* d_ws, size_t ws_size,
                              hipStream_t stream) {
    const float* S   = (const float*)d_in[0];  // [256][2048]
    const float* mem = (const float*)d_in[1];  // [65536][64]
    const float* Wk  = (const float*)d_in[2];  // [256][2048]
    const float* bk  = (const float*)d_in[3];  // [256]
    const float* Wb  = (const float*)d_in[4];  // [4][2048]
    const float* bb  = (const float*)d_in[5];  // [4]
    float* out = (float*)d_out;                // [1024][65536]

    // workspace layout (floats), total ~23.3 MB
    float* w0    = (float*)d_ws;
    float* memT  = w0;                                   // 64*65536
    float* WkT   = memT  + (size_t)LL * MM;              // 2048*256
    float* kpart = WkT   + (size_t)RR * KEYS;            // 8*256*256
    float* qT    = kpart + (size_t)8 * BB * KEYS;        // 64*1024
    float* pmax  = qT    + (size_t)LL * NROW;            // 1024*256
    float* psum  = pmax  + (size_t)NROW * 256;           // 1024*256
    float* rstat = psum  + (size_t)NROW * 256;           // 1024*2

    transpose_k<<<dim3(MM / 64, 1), 256, 0, stream>>>(mem, memT, MM, LL);
    transpose_k<<<dim3(BB / 64, RR / 64), 256, 0, stream>>>(Wk, WkT, KEYS, RR);
    k0_keys   <<<dim3(32, 8),  256, 0, stream>>>(S, WkT, kpart);
    k1_finalize<<<NROW,        256, 0, stream>>>(S, kpart, bk, Wb, bb, qT);
    k2_partial<<<64 * 64,      256, 0, stream>>>(memT, qT, pmax, psum);
    k3_combine<<<NROW,         256, 0, stream>>>(pmax, psum, rstat);
    k4_out    <<<64 * 64,      256, 0, stream>>>(memT, qT, rstat, out);
}